// Round 1
// baseline (2633.233 us; speedup 1.0000x reference)
//
#include <hip/hip_runtime.h>
#include <cmath>

#define BATCH 16
#define NROI 100
#define FLATD 10000

// ---------- helpers ----------
__device__ __forceinline__ float sigmoidf(float x) { return 1.0f / (1.0f + expf(-x)); }
__device__ __forceinline__ float geluf(float x) { return 0.5f * x * (1.0f + erff(x * 0.70710678118654752f)); }

// ---------- K1: transpose A [16,10000] -> At [10000,16] ----------
__global__ __launch_bounds__(256) void transpose_A(const float* __restrict__ A, float* __restrict__ At) {
    int e = blockIdx.x * 256 + threadIdx.x;   // 160000 total
    int m = e & 15;
    int k = e >> 4;
    At[e] = A[(size_t)m * FLATD + k];
}

// ---------- K2: big GEMM pre[16,10000] += A @ gbW (split-K, atomics) ----------
// grid (20 col-tiles, 50 k-splits), block 256; 2 cols/thread via float2
__global__ __launch_bounds__(256) void gemm1(const float* __restrict__ At, const float* __restrict__ W,
                                             float* __restrict__ pre) {
    int col = blockIdx.x * 512 + threadIdx.x * 2;
    if (col >= FLATD) return;
    int k0 = blockIdx.y * 200, k1 = k0 + 200;
    float acc0[16], acc1[16];
#pragma unroll
    for (int m = 0; m < 16; ++m) { acc0[m] = 0.f; acc1[m] = 0.f; }
#pragma unroll 4
    for (int k = k0; k < k1; ++k) {
        float2 w = *reinterpret_cast<const float2*>(W + (size_t)k * FLATD + col);
        const float* a = At + k * 16;   // wave-uniform -> s_load
#pragma unroll
        for (int m = 0; m < 16; ++m) { acc0[m] += a[m] * w.x; acc1[m] += a[m] * w.y; }
    }
#pragma unroll
    for (int m = 0; m < 16; ++m) {
        atomicAdd(pre + (size_t)m * FLATD + col, acc0[m]);
        atomicAdd(pre + (size_t)m * FLATD + col + 1, acc1[m]);
    }
}

// ---------- K3: symmetrize + sigmoid + row stats ----------
__global__ __launch_bounds__(256) void sym_stats(const float* __restrict__ pre, const float* __restrict__ gbb,
                                                 float* __restrict__ adjsym, float* __restrict__ bft) {
    __shared__ float s_adj[NROI][NROI + 1];
    int b = blockIdx.x;
    const float* pb = pre + (size_t)b * FLATD;
    for (int idx = threadIdx.x; idx < FLATD; idx += 256) {
        int i = idx / NROI, j = idx % NROI;
        float p = pb[i * NROI + j] + gbb[i * NROI + j];
        float q = pb[j * NROI + i] + gbb[j * NROI + i];
        float v = 0.5f * (sigmoidf(p) + sigmoidf(q));
        s_adj[i][j] = v;
        adjsym[(size_t)b * FLATD + idx] = v;
    }
    __syncthreads();
    if (threadIdx.x < NROI) {
        int i = threadIdx.x;
        float sum = 0.f, sumsq = 0.f;
        for (int j = 0; j < NROI; ++j) { float v = s_adj[i][j]; sum += v; sumsq += v * v; }
        float mean = sum * 0.01f;
        float var = (sumsq - sum * sum * 0.01f) * (1.0f / 99.0f);
        var = fmaxf(var, 0.f);
        bft[(b * NROI + i) * 2 + 0] = mean;
        bft[(b * NROI + i) * 2 + 1] = sqrtf(var) + 1e-6f;
    }
}

// ---------- K4: exact 0.75-quantile via in-LDS bitonic sort (16384 padded) ----------
__global__ __launch_bounds__(1024) void quantile_kernel(const float* __restrict__ adjsym, float* __restrict__ thr) {
    extern __shared__ float s[];
    int b = blockIdx.x;
    for (int t = threadIdx.x; t < 16384; t += 1024)
        s[t] = (t < FLATD) ? adjsym[(size_t)b * FLATD + t] : 2.0f;   // sigmoid avg < 1 < 2 pad
    __syncthreads();
    for (int k = 2; k <= 16384; k <<= 1) {
        for (int j = k >> 1; j > 0; j >>= 1) {
            for (int t = threadIdx.x; t < 16384; t += 1024) {
                int ixj = t ^ j;
                if (ixj > t) {
                    bool up = (t & k) == 0;
                    float a = s[t], c = s[ixj];
                    if ((a > c) == up) { s[t] = c; s[ixj] = a; }
                }
            }
            __syncthreads();
        }
    }
    if (threadIdx.x == 0) thr[b] = s[7499] + 0.25f * (s[7500] - s[7499]);
}

// ---------- K5: feature enhancer + LayerNorm -> x0 [1600,16] ----------
__global__ __launch_bounds__(256) void enhancer(const float* __restrict__ bft,
                                                const float* __restrict__ W1, const float* __restrict__ b1,
                                                const float* __restrict__ W2, const float* __restrict__ b2,
                                                const float* __restrict__ g, const float* __restrict__ beta,
                                                float* __restrict__ x0) {
    int idx = blockIdx.x * 256 + threadIdx.x;
    if (idx >= BATCH * NROI) return;
    float f0 = bft[idx * 2 + 0], f1 = bft[idx * 2 + 1];
    float h8[8];
#pragma unroll
    for (int u = 0; u < 8; ++u) h8[u] = geluf(W1[u] * f0 + W1[8 + u] * f1 + b1[u]);
    float o[16];
    float mu = 0.f;
#pragma unroll
    for (int v = 0; v < 16; ++v) {
        float t = b2[v];
#pragma unroll
        for (int u = 0; u < 8; ++u) t += h8[u] * W2[u * 16 + v];
        o[v] = t; mu += t;
    }
    mu *= (1.0f / 16.0f);
    float var = 0.f;
#pragma unroll
    for (int v = 0; v < 16; ++v) { float d = o[v] - mu; var += d * d; }
    var *= (1.0f / 16.0f);
    float inv = rsqrtf(var + 1e-5f);
#pragma unroll
    for (int v = 0; v < 16; ++v) x0[idx * 16 + v] = (o[v] - mu) * inv * g[v] + beta[v];
}

// ---------- K6: generic fp32 tiled GEMM out[1600,Nout] = X[1600,K] @ W[K,Nout] + bias ----------
// block 256 (16x16), tile 64x128, thread 4x8
__global__ __launch_bounds__(256) void proj_gemm(const float* __restrict__ X, const float* __restrict__ W,
                                                 const float* __restrict__ bias, float* __restrict__ out,
                                                 int K, int Nout) {
    __shared__ float As[16][65];
    __shared__ float Bs[16][128];
    int tid = threadIdx.x;
    int tm = tid & 15, tn = tid >> 4;
    int m0 = blockIdx.x * 64, n0 = blockIdx.y * 128;
    float acc[4][8];
#pragma unroll
    for (int r = 0; r < 4; ++r)
#pragma unroll
        for (int c = 0; c < 8; ++c) acc[r][c] = 0.f;
    for (int k0 = 0; k0 < K; k0 += 16) {
        for (int e = tid; e < 64 * 16; e += 256) {
            int kk = e & 15, mm = e >> 4;
            As[kk][mm] = X[(size_t)(m0 + mm) * K + k0 + kk];
        }
        for (int e = tid; e < 16 * 128; e += 256) {
            int nn = e & 127, kk = e >> 7;
            Bs[kk][nn] = W[(size_t)(k0 + kk) * Nout + n0 + nn];
        }
        __syncthreads();
#pragma unroll
        for (int kk = 0; kk < 16; ++kk) {
            float a[4], bb[8];
#pragma unroll
            for (int r = 0; r < 4; ++r) a[r] = As[kk][tm * 4 + r];
#pragma unroll
            for (int c = 0; c < 8; ++c) bb[c] = Bs[kk][tn * 8 + c];
#pragma unroll
            for (int r = 0; r < 4; ++r)
#pragma unroll
                for (int c = 0; c < 8; ++c) acc[r][c] += a[r] * bb[c];
        }
        __syncthreads();
    }
#pragma unroll
    for (int r = 0; r < 4; ++r)
#pragma unroll
        for (int c = 0; c < 8; ++c)
            out[(size_t)(m0 + tm * 4 + r) * Nout + n0 + tn * 8 + c] = acc[r][c] + bias[n0 + tn * 8 + c];
}

// ---------- K7: GATv2 scores + masked softmax -> alpha_T[b,h,j,i] ----------
// grid (B*H, 2 i-tiles), block 128 (lane = j)
__global__ __launch_bounds__(128) void score_softmax(const float* __restrict__ xl, const float* __restrict__ xr,
                                                     const float* __restrict__ att, const float* __restrict__ adjsym,
                                                     const float* __restrict__ thr, float* __restrict__ alpha,
                                                     int H, int C, int self_loop) {
    __shared__ float e_lds[50][101];
    int bh = blockIdx.x;
    int b = bh / H, h = bh % H;
    int i0 = blockIdx.y * 50;
    int j = threadIdx.x;
    const float* xlrow = xl + ((size_t)(b * NROI + (j < NROI ? j : 0)) * H + h) * C;

    for (int cc = 0; cc < C; cc += 32) {
        float xlr[32];
        if (j < NROI) {
#pragma unroll
            for (int t = 0; t < 32; ++t) xlr[t] = xlrow[cc + t];
        }
        const float* attp = att + h * C + cc;           // uniform -> SGPR
        for (int i = 0; i < 50; ++i) {
            const float* xrrow = xr + ((size_t)(b * NROI + i0 + i) * H + h) * C + cc;  // uniform -> SGPR
            float s = 0.f;
#pragma unroll
            for (int t = 0; t < 32; ++t) {
                float z = xlr[t] + xrrow[t];
                z = fmaxf(z, 0.2f * z);                 // leaky relu, slope<1
                s += attp[t] * z;
            }
            if (j < NROI) {
                if (cc == 0) e_lds[i][j] = s; else e_lds[i][j] += s;
            }
        }
    }
    __syncthreads();
    // softmax: lane = i (50 active)
    if (threadIdx.x < 50) {
        int i = threadIdx.x;
        int gi = i0 + i;
        const float* arow = adjsym + (size_t)b * FLATD + gi * NROI;
        float tb = thr[b];
        float mx = -3.0e38f;
        for (int jj = 0; jj < NROI; ++jj) {
            float e = e_lds[i][jj];
            bool edge = (arow[jj] > tb) || (self_loop && jj == gi);
            float em = edge ? e : -1.0e9f;
            e_lds[i][jj] = em;
            mx = fmaxf(mx, em);
        }
        float sum = 0.f;
        for (int jj = 0; jj < NROI; ++jj) sum += expf(e_lds[i][jj] - mx);
        float inv = 1.0f / sum;
        float* ab = alpha + (size_t)(b * H + h) * FLATD + gi;  // write column gi, stride 100 over j
        for (int jj = 0; jj < NROI; ++jj) {
            float em = e_lds[i][jj];
            ab[jj * NROI] = (em > -0.5e9f) ? expf(em - mx) * inv : 0.0f;
        }
    }
}

// ---------- K8: aggregation out[b,i,h,c] = sum_j alpha * xl  (+bias, gelu, optional pool) ----------
// grid (B*H, C/128, 4 i-tiles of 25), block 128 (lane = c within 128-chunk)
__global__ __launch_bounds__(128) void agg_kernel(const float* __restrict__ xl, const float* __restrict__ alpha,
                                                  const float* __restrict__ bias, float* __restrict__ yout,
                                                  float* __restrict__ pool_out, int H, int C, int pool) {
    __shared__ float s_xl[NROI * 128];
    int bh = blockIdx.x;
    int b = bh / H, h = bh % H;
    int ch = blockIdx.y;
    int i0 = blockIdx.z * 25;
    int tid = threadIdx.x;
    for (int e = tid; e < NROI * 128; e += 128) {
        int jj = e >> 7, t = e & 127;
        s_xl[e] = xl[((size_t)(b * NROI + jj) * H + h) * C + ch * 128 + t];
    }
    __syncthreads();
    int cglob = ch * 128 + tid;
    float bval = bias[h * C + cglob];
    const float* ap = alpha + (size_t)(b * H + h) * FLATD;
    for (int ib = 0; ib < 25; ib += 8) {
        int nb = (25 - ib) >= 8 ? 8 : (25 - ib);
        float acc[8] = {0.f, 0.f, 0.f, 0.f, 0.f, 0.f, 0.f, 0.f};
        if (nb == 8) {
            for (int jj = 0; jj < NROI; ++jj) {
                float xlv = s_xl[jj * 128 + tid];
                const float* ar = ap + jj * NROI + i0 + ib;   // uniform -> s_load_dwordx8
#pragma unroll
                for (int t = 0; t < 8; ++t) acc[t] += ar[t] * xlv;
            }
        } else {
            for (int jj = 0; jj < NROI; ++jj)
                acc[0] += ap[jj * NROI + i0 + ib] * s_xl[jj * 128 + tid];
        }
        for (int t = 0; t < nb; ++t) {
            int gi = i0 + ib + t;
            float v = geluf(acc[t] + bval);
            if (pool) atomicAdd(pool_out + b * 128 + cglob, 0.01f * v);
            else yout[((size_t)(b * NROI + gi) * H + h) * C + cglob] = v;
        }
    }
}

// ---------- launcher ----------
extern "C" void kernel_launch(void* const* d_in, const int* in_sizes, int n_in,
                              void* d_out, int out_size, void* d_ws, size_t ws_size,
                              hipStream_t stream) {
    const float* A    = (const float*)d_in[0];
    const float* gbW  = (const float*)d_in[1];
    const float* gbb  = (const float*)d_in[2];
    const float* feW1 = (const float*)d_in[3];
    const float* feb1 = (const float*)d_in[4];
    const float* feW2 = (const float*)d_in[5];
    const float* feb2 = (const float*)d_in[6];
    const float* feg  = (const float*)d_in[7];
    const float* febt = (const float*)d_in[8];
    const float* Wl1  = (const float*)d_in[9];
    const float* bl1  = (const float*)d_in[10];
    const float* Wr1  = (const float*)d_in[11];
    const float* br1  = (const float*)d_in[12];
    const float* att1 = (const float*)d_in[13];
    const float* bias1= (const float*)d_in[14];
    const float* Wl2  = (const float*)d_in[15];
    const float* bl2  = (const float*)d_in[16];
    const float* Wr2  = (const float*)d_in[17];
    const float* br2  = (const float*)d_in[18];
    const float* att2 = (const float*)d_in[19];
    const float* bias2= (const float*)d_in[20];
    const float* Wl3  = (const float*)d_in[21];
    const float* bl3  = (const float*)d_in[22];
    const float* Wr3  = (const float*)d_in[23];
    const float* br3  = (const float*)d_in[24];
    const float* att3 = (const float*)d_in[25];
    const float* bias3= (const float*)d_in[26];

    float* ws = (float*)d_ws;
    float* At    = ws + 0;          // 160000
    float* pre   = ws + 160000;     // 160000
    float* adj   = ws + 320000;     // 160000
    float* thr   = ws + 480000;     // 16
    float* bft   = ws + 480016;     // 3200
    float* x0    = ws + 483216;     // 25600
    float* xlbuf = ws + 508816;     // 1638400
    float* xrbuf = ws + 2147216;    // 1638400
    float* ybuf  = ws + 3785616;    // 1638400
    float* alpha = ws + 5424016;    // 1280000  (total ~26.8 MB)

    hipMemsetAsync(pre, 0, 160000 * sizeof(float), stream);
    hipMemsetAsync(d_out, 0, (size_t)out_size * sizeof(float), stream);

    transpose_A<<<625, 256, 0, stream>>>(A, At);
    gemm1<<<dim3(20, 50), 256, 0, stream>>>(At, gbW, pre);
    sym_stats<<<BATCH, 256, 0, stream>>>(pre, gbb, adj, bft);
    quantile_kernel<<<BATCH, 1024, 65536, stream>>>(adj, thr);
    enhancer<<<7, 256, 0, stream>>>(bft, feW1, feb1, feW2, feb2, feg, febt, x0);

    // layer 1: H=8, C=128, no self loops
    proj_gemm<<<dim3(25, 8), 256, 0, stream>>>(x0, Wl1, bl1, xlbuf, 16, 1024);
    proj_gemm<<<dim3(25, 8), 256, 0, stream>>>(x0, Wr1, br1, xrbuf, 16, 1024);
    score_softmax<<<dim3(128, 2), 128, 0, stream>>>(xlbuf, xrbuf, att1, adj, thr, alpha, 8, 128, 0);
    agg_kernel<<<dim3(128, 1, 4), 128, 0, stream>>>(xlbuf, alpha, bias1, ybuf, nullptr, 8, 128, 0);

    // layer 2: H=4, C=256, self loops
    proj_gemm<<<dim3(25, 8), 256, 0, stream>>>(ybuf, Wl2, bl2, xlbuf, 1024, 1024);
    proj_gemm<<<dim3(25, 8), 256, 0, stream>>>(ybuf, Wr2, br2, xrbuf, 1024, 1024);
    score_softmax<<<dim3(64, 2), 128, 0, stream>>>(xlbuf, xrbuf, att2, adj, thr, alpha, 4, 256, 1);
    agg_kernel<<<dim3(64, 2, 4), 128, 0, stream>>>(xlbuf, alpha, bias2, ybuf, nullptr, 4, 256, 0);

    // layer 3: H=1, C=128, self loops, mean-pool into d_out
    proj_gemm<<<dim3(25, 1), 256, 0, stream>>>(ybuf, Wl3, bl3, xlbuf, 1024, 128);
    proj_gemm<<<dim3(25, 1), 256, 0, stream>>>(ybuf, Wr3, br3, xrbuf, 1024, 128);
    score_softmax<<<dim3(16, 2), 128, 0, stream>>>(xlbuf, xrbuf, att3, adj, thr, alpha, 1, 128, 1);
    agg_kernel<<<dim3(16, 1, 4), 128, 0, stream>>>(xlbuf, alpha, bias3, nullptr, (float*)d_out, 1, 128, 1);
}

// Round 2
// 1490.369 us; speedup vs baseline: 1.7668x; 1.7668x over previous
//
#include <hip/hip_runtime.h>
#include <cmath>

#define BATCH 16
#define NROI 100
#define FLATD 10000

typedef __attribute__((ext_vector_type(8))) short s16x8;
typedef __attribute__((ext_vector_type(4))) short s16x4;
typedef __attribute__((ext_vector_type(4))) float f32x4;

// ---------- helpers ----------
__device__ __forceinline__ float sigmoidf(float x) { return 1.0f / (1.0f + expf(-x)); }
__device__ __forceinline__ float geluf(float x) { return 0.5f * x * (1.0f + erff(x * 0.70710678118654752f)); }
__device__ __forceinline__ short f2bf(float x) {
    union { float f; unsigned u; } v; v.f = x;
    unsigned r = v.u + 0x7FFF + ((v.u >> 16) & 1);
    return (short)(r >> 16);
}

// ---------- K1: transpose A [16,10000] -> At [10000,16] ----------
__global__ __launch_bounds__(256) void transpose_A(const float* __restrict__ A, float* __restrict__ At) {
    int e = blockIdx.x * 256 + threadIdx.x;   // 160000 total
    int m = e & 15;
    int k = e >> 4;
    At[e] = A[(size_t)m * FLATD + k];
}

// ---------- K2: big GEMM pre[16,10000] += A @ gbW (split-K, atomics) ----------
__global__ __launch_bounds__(256) void gemm1(const float* __restrict__ At, const float* __restrict__ W,
                                             float* __restrict__ pre) {
    int col = blockIdx.x * 512 + threadIdx.x * 2;
    if (col >= FLATD) return;
    int k0 = blockIdx.y * 200, k1 = k0 + 200;
    float acc0[16], acc1[16];
#pragma unroll
    for (int m = 0; m < 16; ++m) { acc0[m] = 0.f; acc1[m] = 0.f; }
#pragma unroll 4
    for (int k = k0; k < k1; ++k) {
        float2 w = *reinterpret_cast<const float2*>(W + (size_t)k * FLATD + col);
        const float* a = At + k * 16;   // wave-uniform -> s_load
#pragma unroll
        for (int m = 0; m < 16; ++m) { acc0[m] += a[m] * w.x; acc1[m] += a[m] * w.y; }
    }
#pragma unroll
    for (int m = 0; m < 16; ++m) {
        atomicAdd(pre + (size_t)m * FLATD + col, acc0[m]);
        atomicAdd(pre + (size_t)m * FLATD + col + 1, acc1[m]);
    }
}

// ---------- K3: symmetrize + sigmoid + row stats ----------
__global__ __launch_bounds__(256) void sym_stats(const float* __restrict__ pre, const float* __restrict__ gbb,
                                                 float* __restrict__ adjsym, float* __restrict__ bft) {
    __shared__ float s_adj[NROI][NROI + 1];
    int b = blockIdx.x;
    const float* pb = pre + (size_t)b * FLATD;
    for (int idx = threadIdx.x; idx < FLATD; idx += 256) {
        int i = idx / NROI, j = idx % NROI;
        float p = pb[i * NROI + j] + gbb[i * NROI + j];
        float q = pb[j * NROI + i] + gbb[j * NROI + i];
        float v = 0.5f * (sigmoidf(p) + sigmoidf(q));
        s_adj[i][j] = v;
        adjsym[(size_t)b * FLATD + idx] = v;
    }
    __syncthreads();
    if (threadIdx.x < NROI) {
        int i = threadIdx.x;
        float sum = 0.f, sumsq = 0.f;
        for (int j = 0; j < NROI; ++j) { float v = s_adj[i][j]; sum += v; sumsq += v * v; }
        float mean = sum * 0.01f;
        float var = (sumsq - sum * sum * 0.01f) * (1.0f / 99.0f);
        var = fmaxf(var, 0.f);
        bft[(b * NROI + i) * 2 + 0] = mean;
        bft[(b * NROI + i) * 2 + 1] = sqrtf(var) + 1e-6f;
    }
}

// ---------- K4: exact 0.75-quantile via in-LDS bitonic sort (16384 padded) ----------
__global__ __launch_bounds__(1024) void quantile_kernel(const float* __restrict__ adjsym, float* __restrict__ thr) {
    extern __shared__ float s[];
    int b = blockIdx.x;
    for (int t = threadIdx.x; t < 16384; t += 1024)
        s[t] = (t < FLATD) ? adjsym[(size_t)b * FLATD + t] : 2.0f;
    __syncthreads();
    for (int k = 2; k <= 16384; k <<= 1) {
        for (int j = k >> 1; j > 0; j >>= 1) {
            for (int t = threadIdx.x; t < 16384; t += 1024) {
                int ixj = t ^ j;
                if (ixj > t) {
                    bool up = (t & k) == 0;
                    float a = s[t], c = s[ixj];
                    if ((a > c) == up) { s[t] = c; s[ixj] = a; }
                }
            }
            __syncthreads();
        }
    }
    if (threadIdx.x == 0) thr[b] = s[7499] + 0.25f * (s[7500] - s[7499]);
}

// ---------- K5: feature enhancer + LayerNorm -> x0 [1600,16] ----------
__global__ __launch_bounds__(256) void enhancer(const float* __restrict__ bft,
                                                const float* __restrict__ W1, const float* __restrict__ b1,
                                                const float* __restrict__ W2, const float* __restrict__ b2,
                                                const float* __restrict__ g, const float* __restrict__ beta,
                                                float* __restrict__ x0) {
    int idx = blockIdx.x * 256 + threadIdx.x;
    if (idx >= BATCH * NROI) return;
    float f0 = bft[idx * 2 + 0], f1 = bft[idx * 2 + 1];
    float h8[8];
#pragma unroll
    for (int u = 0; u < 8; ++u) h8[u] = geluf(W1[u] * f0 + W1[8 + u] * f1 + b1[u]);
    float o[16];
    float mu = 0.f;
#pragma unroll
    for (int v = 0; v < 16; ++v) {
        float t = b2[v];
#pragma unroll
        for (int u = 0; u < 8; ++u) t += h8[u] * W2[u * 16 + v];
        o[v] = t; mu += t;
    }
    mu *= (1.0f / 16.0f);
    float var = 0.f;
#pragma unroll
    for (int v = 0; v < 16; ++v) { float d = o[v] - mu; var += d * d; }
    var *= (1.0f / 16.0f);
    float inv = rsqrtf(var + 1e-5f);
#pragma unroll
    for (int v = 0; v < 16; ++v) x0[idx * 16 + v] = (o[v] - mu) * inv * g[v] + beta[v];
}

// ---------- K6: fp32 tiled GEMM (layer 1 only, K=16) ----------
__global__ __launch_bounds__(256) void proj_gemm(const float* __restrict__ X, const float* __restrict__ W,
                                                 const float* __restrict__ bias, float* __restrict__ out,
                                                 int K, int Nout) {
    __shared__ float As[16][65];
    __shared__ float Bs[16][128];
    int tid = threadIdx.x;
    int tm = tid & 15, tn = tid >> 4;
    int m0 = blockIdx.x * 64, n0 = blockIdx.y * 128;
    float acc[4][8];
#pragma unroll
    for (int r = 0; r < 4; ++r)
#pragma unroll
        for (int c = 0; c < 8; ++c) acc[r][c] = 0.f;
    for (int k0 = 0; k0 < K; k0 += 16) {
        for (int e = tid; e < 64 * 16; e += 256) {
            int kk = e & 15, mm = e >> 4;
            As[kk][mm] = X[(size_t)(m0 + mm) * K + k0 + kk];
        }
        for (int e = tid; e < 16 * 128; e += 256) {
            int nn = e & 127, kk = e >> 7;
            Bs[kk][nn] = W[(size_t)(k0 + kk) * Nout + n0 + nn];
        }
        __syncthreads();
#pragma unroll
        for (int kk = 0; kk < 16; ++kk) {
            float a[4], bb[8];
#pragma unroll
            for (int r = 0; r < 4; ++r) a[r] = As[kk][tm * 4 + r];
#pragma unroll
            for (int c = 0; c < 8; ++c) bb[c] = Bs[kk][tn * 8 + c];
#pragma unroll
            for (int r = 0; r < 4; ++r)
#pragma unroll
                for (int c = 0; c < 8; ++c) acc[r][c] += a[r] * bb[c];
        }
        __syncthreads();
    }
#pragma unroll
    for (int r = 0; r < 4; ++r)
#pragma unroll
        for (int c = 0; c < 8; ++c)
            out[(size_t)(m0 + tm * 4 + r) * Nout + n0 + tn * 8 + c] = acc[r][c] + bias[n0 + tn * 8 + c];
}

// ---------- K6b: convert fp32 -> bf16 (row-major copy) ----------
__global__ __launch_bounds__(256) void convX(const float* __restrict__ in, short* __restrict__ out) {
    int e = (blockIdx.x * 256 + threadIdx.x) * 4;
    float4 v = *reinterpret_cast<const float4*>(in + e);
    s16x4 o;
    o[0] = f2bf(v.x); o[1] = f2bf(v.y); o[2] = f2bf(v.z); o[3] = f2bf(v.w);
    *reinterpret_cast<s16x4*>(out + e) = o;
}

// ---------- K6c: transpose + convert W [K,N] fp32 -> Wt [N,K] bf16 ----------
__global__ __launch_bounds__(256) void convT(const float* __restrict__ in, short* __restrict__ out,
                                             int K, int N) {
    __shared__ float t[32][33];
    int n0 = blockIdx.x * 32, k0 = blockIdx.y * 32;
    int tx = threadIdx.x & 31, ty = threadIdx.x >> 5;   // ty 0..7
#pragma unroll
    for (int i = 0; i < 32; i += 8)
        t[ty + i][tx] = in[(size_t)(k0 + ty + i) * N + n0 + tx];
    __syncthreads();
#pragma unroll
    for (int i = 0; i < 32; i += 8)
        out[(size_t)(n0 + ty + i) * K + k0 + tx] = f2bf(t[tx][ty + i]);
}

// ---------- K6d: bf16 MFMA GEMM out[M,N] = Xb[M,K] @ Wt[N,K]^T + bias ----------
// tile 64x64, block 256 = 4 waves (2x2), each wave 32x32 via 2x2 MFMA 16x16x32
__global__ __launch_bounds__(256) void mfma_proj(const short* __restrict__ Xb,
                                                 const short* __restrict__ WtL, const short* __restrict__ WtR,
                                                 const float* __restrict__ biasL, const float* __restrict__ biasR,
                                                 float* __restrict__ outL, float* __restrict__ outR,
                                                 int K, int N) {
    __shared__ short As[64 * 40];
    __shared__ short Bs[64 * 40];
    const short* Wt  = blockIdx.z ? WtR : WtL;
    const float* bias = blockIdx.z ? biasR : biasL;
    float* out = blockIdx.z ? outR : outL;
    int m0 = blockIdx.x * 64, n0 = blockIdx.y * 64;
    int tid = threadIdx.x;
    int row = tid >> 2, part = tid & 3;
    int lane = tid & 63, wave = tid >> 6;
    int wm = wave & 1, wn = wave >> 1;
    int quad = lane >> 4, l16 = lane & 15;
    f32x4 acc00 = {}, acc01 = {}, acc10 = {}, acc11 = {};
    const short* gA = Xb + (size_t)(m0 + row) * K + part * 8;
    const short* gB = Wt + (size_t)(n0 + row) * K + part * 8;
    short* sA = As + row * 40 + part * 8;
    short* sB = Bs + row * 40 + part * 8;
    const short* fA = As + (wm * 32 + l16) * 40 + quad * 8;
    const short* fB = Bs + (wn * 32 + l16) * 40 + quad * 8;
    for (int k0 = 0; k0 < K; k0 += 32) {
        *reinterpret_cast<s16x8*>(sA) = *reinterpret_cast<const s16x8*>(gA + k0);
        *reinterpret_cast<s16x8*>(sB) = *reinterpret_cast<const s16x8*>(gB + k0);
        __syncthreads();
        s16x8 a0 = *reinterpret_cast<const s16x8*>(fA);
        s16x8 a1 = *reinterpret_cast<const s16x8*>(fA + 16 * 40);
        s16x8 b0 = *reinterpret_cast<const s16x8*>(fB);
        s16x8 b1 = *reinterpret_cast<const s16x8*>(fB + 16 * 40);
        acc00 = __builtin_amdgcn_mfma_f32_16x16x32_bf16(a0, b0, acc00, 0, 0, 0);
        acc01 = __builtin_amdgcn_mfma_f32_16x16x32_bf16(a0, b1, acc01, 0, 0, 0);
        acc10 = __builtin_amdgcn_mfma_f32_16x16x32_bf16(a1, b0, acc10, 0, 0, 0);
        acc11 = __builtin_amdgcn_mfma_f32_16x16x32_bf16(a1, b1, acc11, 0, 0, 0);
        __syncthreads();
    }
    // C/D: col = l16, row = quad*4 + reg  [m89/m91-verified]
#pragma unroll
    for (int tm = 0; tm < 2; ++tm)
#pragma unroll
        for (int tn = 0; tn < 2; ++tn) {
            const f32x4& a = tm == 0 ? (tn == 0 ? acc00 : acc01) : (tn == 0 ? acc10 : acc11);
            int mbase = m0 + wm * 32 + tm * 16 + quad * 4;
            int n = n0 + wn * 32 + tn * 16 + l16;
            float bv = bias[n];
#pragma unroll
            for (int r = 0; r < 4; ++r)
                out[(size_t)(mbase + r) * N + n] = a[r] + bv;
        }
}

// ---------- K7: GATv2 scores + masked softmax -> alpha_T[b,h,j,i] ----------
__global__ __launch_bounds__(128) void score_softmax(const float* __restrict__ xl, const float* __restrict__ xr,
                                                     const float* __restrict__ att, const float* __restrict__ adjsym,
                                                     const float* __restrict__ thr, float* __restrict__ alpha,
                                                     int H, int C, int self_loop) {
    __shared__ float e_lds[50][101];
    int bh = blockIdx.x;
    int b = bh / H, h = bh % H;
    int i0 = blockIdx.y * 50;
    int j = threadIdx.x;
    const float* xlrow = xl + ((size_t)(b * NROI + (j < NROI ? j : 0)) * H + h) * C;

    for (int cc = 0; cc < C; cc += 32) {
        float xlr[32];
        if (j < NROI) {
#pragma unroll
            for (int t = 0; t < 32; ++t) xlr[t] = xlrow[cc + t];
        }
        const float* attp = att + h * C + cc;           // uniform -> SGPR
        for (int i = 0; i < 50; ++i) {
            const float* xrrow = xr + ((size_t)(b * NROI + i0 + i) * H + h) * C + cc;  // uniform -> SGPR
            float s = 0.f;
#pragma unroll
            for (int t = 0; t < 32; ++t) {
                float z = xlr[t] + xrrow[t];
                z = fmaxf(z, 0.2f * z);
                s += attp[t] * z;
            }
            if (j < NROI) {
                if (cc == 0) e_lds[i][j] = s; else e_lds[i][j] += s;
            }
        }
    }
    __syncthreads();
    if (threadIdx.x < 50) {
        int i = threadIdx.x;
        int gi = i0 + i;
        const float* arow = adjsym + (size_t)b * FLATD + gi * NROI;
        float tb = thr[b];
        float mx = -3.0e38f;
        for (int jj = 0; jj < NROI; ++jj) {
            float e = e_lds[i][jj];
            bool edge = (arow[jj] > tb) || (self_loop && jj == gi);
            float em = edge ? e : -1.0e9f;
            e_lds[i][jj] = em;
            mx = fmaxf(mx, em);
        }
        float sum = 0.f;
        for (int jj = 0; jj < NROI; ++jj) sum += expf(e_lds[i][jj] - mx);
        float inv = 1.0f / sum;
        float* ab = alpha + (size_t)(b * H + h) * FLATD + gi;
        for (int jj = 0; jj < NROI; ++jj) {
            float em = e_lds[i][jj];
            ab[jj * NROI] = (em > -0.5e9f) ? expf(em - mx) * inv : 0.0f;
        }
    }
}

// ---------- K8: aggregation ----------
__global__ __launch_bounds__(128) void agg_kernel(const float* __restrict__ xl, const float* __restrict__ alpha,
                                                  const float* __restrict__ bias, float* __restrict__ yout,
                                                  float* __restrict__ pool_out, int H, int C, int pool) {
    __shared__ float s_xl[NROI * 128];
    int bh = blockIdx.x;
    int b = bh / H, h = bh % H;
    int ch = blockIdx.y;
    int i0 = blockIdx.z * 25;
    int tid = threadIdx.x;
    for (int e = tid; e < NROI * 128; e += 128) {
        int jj = e >> 7, t = e & 127;
        s_xl[e] = xl[((size_t)(b * NROI + jj) * H + h) * C + ch * 128 + t];
    }
    __syncthreads();
    int cglob = ch * 128 + tid;
    float bval = bias[h * C + cglob];
    const float* ap = alpha + (size_t)(b * H + h) * FLATD;
    for (int ib = 0; ib < 25; ib += 8) {
        int nb = (25 - ib) >= 8 ? 8 : (25 - ib);
        float acc[8] = {0.f, 0.f, 0.f, 0.f, 0.f, 0.f, 0.f, 0.f};
        if (nb == 8) {
            for (int jj = 0; jj < NROI; ++jj) {
                float xlv = s_xl[jj * 128 + tid];
                const float* ar = ap + jj * NROI + i0 + ib;
#pragma unroll
                for (int t = 0; t < 8; ++t) acc[t] += ar[t] * xlv;
            }
        } else {
            for (int jj = 0; jj < NROI; ++jj)
                acc[0] += ap[jj * NROI + i0 + ib] * s_xl[jj * 128 + tid];
        }
        for (int t = 0; t < nb; ++t) {
            int gi = i0 + ib + t;
            float v = geluf(acc[t] + bval);
            if (pool) atomicAdd(pool_out + b * 128 + cglob, 0.01f * v);
            else yout[((size_t)(b * NROI + gi) * H + h) * C + cglob] = v;
        }
    }
}

// ---------- launcher ----------
extern "C" void kernel_launch(void* const* d_in, const int* in_sizes, int n_in,
                              void* d_out, int out_size, void* d_ws, size_t ws_size,
                              hipStream_t stream) {
    const float* A    = (const float*)d_in[0];
    const float* gbW  = (const float*)d_in[1];
    const float* gbb  = (const float*)d_in[2];
    const float* feW1 = (const float*)d_in[3];
    const float* feb1 = (const float*)d_in[4];
    const float* feW2 = (const float*)d_in[5];
    const float* feb2 = (const float*)d_in[6];
    const float* feg  = (const float*)d_in[7];
    const float* febt = (const float*)d_in[8];
    const float* Wl1  = (const float*)d_in[9];
    const float* bl1  = (const float*)d_in[10];
    const float* Wr1  = (const float*)d_in[11];
    const float* br1  = (const float*)d_in[12];
    const float* att1 = (const float*)d_in[13];
    const float* bias1= (const float*)d_in[14];
    const float* Wl2  = (const float*)d_in[15];
    const float* bl2  = (const float*)d_in[16];
    const float* Wr2  = (const float*)d_in[17];
    const float* br2  = (const float*)d_in[18];
    const float* att2 = (const float*)d_in[19];
    const float* bias2= (const float*)d_in[20];
    const float* Wl3  = (const float*)d_in[21];
    const float* bl3  = (const float*)d_in[22];
    const float* Wr3  = (const float*)d_in[23];
    const float* br3  = (const float*)d_in[24];
    const float* att3 = (const float*)d_in[25];
    const float* bias3= (const float*)d_in[26];

    float* ws = (float*)d_ws;
    float* At    = ws + 0;          // 160000
    float* pre   = ws + 160000;     // 160000
    float* adj   = ws + 320000;     // 160000
    float* thr   = ws + 480000;     // 16
    float* bft   = ws + 480016;     // 3200
    float* x0    = ws + 483216;     // 25600
    float* xlbuf = ws + 508816;     // 1638400
    float* xrbuf = ws + 2147216;    // 1638400
    float* ybuf  = ws + 3785616;    // 1638400
    float* alpha = ws + 5424016;    // 1280000  (Xb aliases here: 819200 floats)
    short* Xb    = (short*)(ws + 5424016);
    short* Wt2l  = (short*)(ws + 6704016);   // 1,048,576 shorts = 524288 floats
    short* Wt2r  = (short*)(ws + 7228304);
    short* Wt3l  = (short*)(ws + 7752592);   // 131072 shorts = 65536 floats
    short* Wt3r  = (short*)(ws + 7818128);   // end = 7,883,664 floats ~ 31.5 MB

    hipMemsetAsync(pre, 0, 160000 * sizeof(float), stream);
    hipMemsetAsync(d_out, 0, (size_t)out_size * sizeof(float), stream);

    transpose_A<<<625, 256, 0, stream>>>(A, At);
    gemm1<<<dim3(20, 50), 256, 0, stream>>>(At, gbW, pre);
    sym_stats<<<BATCH, 256, 0, stream>>>(pre, gbb, adj, bft);
    quantile_kernel<<<BATCH, 1024, 65536, stream>>>(adj, thr);
    enhancer<<<7, 256, 0, stream>>>(bft, feW1, feb1, feW2, feb2, feg, febt, x0);

    // weight conversions (constant inputs, redone per call)
    convT<<<dim3(32, 32), 256, 0, stream>>>(Wl2, Wt2l, 1024, 1024);
    convT<<<dim3(32, 32), 256, 0, stream>>>(Wr2, Wt2r, 1024, 1024);
    convT<<<dim3(4, 32), 256, 0, stream>>>(Wl3, Wt3l, 1024, 128);
    convT<<<dim3(4, 32), 256, 0, stream>>>(Wr3, Wt3r, 1024, 128);

    // layer 1: H=8, C=128, no self loops (K=16 -> fp32 path)
    proj_gemm<<<dim3(25, 8), 256, 0, stream>>>(x0, Wl1, bl1, xlbuf, 16, 1024);
    proj_gemm<<<dim3(25, 8), 256, 0, stream>>>(x0, Wr1, br1, xrbuf, 16, 1024);
    score_softmax<<<dim3(128, 2), 128, 0, stream>>>(xlbuf, xrbuf, att1, adj, thr, alpha, 8, 128, 0);
    agg_kernel<<<dim3(128, 1, 4), 128, 0, stream>>>(xlbuf, alpha, bias1, ybuf, nullptr, 8, 128, 0);

    // layer 2: H=4, C=256, self loops (MFMA path)
    convX<<<1600, 256, 0, stream>>>(ybuf, Xb);
    mfma_proj<<<dim3(25, 16, 2), 256, 0, stream>>>(Xb, Wt2l, Wt2r, bl2, br2, xlbuf, xrbuf, 1024, 1024);
    score_softmax<<<dim3(64, 2), 128, 0, stream>>>(xlbuf, xrbuf, att2, adj, thr, alpha, 4, 256, 1);
    agg_kernel<<<dim3(64, 2, 4), 128, 0, stream>>>(xlbuf, alpha, bias2, ybuf, nullptr, 4, 256, 0);

    // layer 3: H=1, C=128, self loops (MFMA path), mean-pool into d_out
    convX<<<1600, 256, 0, stream>>>(ybuf, Xb);
    mfma_proj<<<dim3(25, 2, 2), 256, 0, stream>>>(Xb, Wt3l, Wt3r, bl3, br3, xlbuf, xrbuf, 1024, 128);
    score_softmax<<<dim3(16, 2), 128, 0, stream>>>(xlbuf, xrbuf, att3, adj, thr, alpha, 1, 128, 1);
    agg_kernel<<<dim3(16, 1, 4), 128, 0, stream>>>(xlbuf, alpha, bias3, nullptr, (float*)d_out, 1, 128, 1);
}

// Round 3
// 1111.158 us; speedup vs baseline: 2.3698x; 1.3413x over previous
//
#include <hip/hip_runtime.h>
#include <cmath>

#define BATCH 16
#define NROI 100
#define FLATD 10000

typedef __attribute__((ext_vector_type(8))) short s16x8;
typedef __attribute__((ext_vector_type(4))) short s16x4;
typedef __attribute__((ext_vector_type(4))) float f32x4;

// ---------- helpers ----------
__device__ __forceinline__ float sigmoidf(float x) { return 1.0f / (1.0f + expf(-x)); }
__device__ __forceinline__ float geluf(float x) { return 0.5f * x * (1.0f + erff(x * 0.70710678118654752f)); }
__device__ __forceinline__ short f2bf(float x) {
    union { float f; unsigned u; } v; v.f = x;
    unsigned r = v.u + 0x7FFF + ((v.u >> 16) & 1);
    return (short)(r >> 16);
}

// ---------- K1: transpose A [16,10000] -> At [10000,16] ----------
__global__ __launch_bounds__(256) void transpose_A(const float* __restrict__ A, float* __restrict__ At) {
    int e = blockIdx.x * 256 + threadIdx.x;
    int m = e & 15;
    int k = e >> 4;
    At[e] = A[(size_t)m * FLATD + k];
}

// ---------- K2: big GEMM partials part[ky][16][10000] = A @ gbW slice (NO atomics) ----------
// grid (20 col-tiles, 25 k-splits), block 256; 2 cols/thread via float2
__global__ __launch_bounds__(256) void gemm1_part(const float* __restrict__ At, const float* __restrict__ W,
                                                  float* __restrict__ part) {
    int col = blockIdx.x * 512 + threadIdx.x * 2;
    int ky = blockIdx.y;
    int k0 = ky * 400, k1 = k0 + 400;
    float acc0[16], acc1[16];
#pragma unroll
    for (int m = 0; m < 16; ++m) { acc0[m] = 0.f; acc1[m] = 0.f; }
#pragma unroll 4
    for (int k = k0; k < k1; ++k) {
        float2 w = *reinterpret_cast<const float2*>(W + (size_t)k * FLATD + col);
        const float* a = At + k * 16;   // wave-uniform -> s_load
#pragma unroll
        for (int m = 0; m < 16; ++m) { acc0[m] += a[m] * w.x; acc1[m] += a[m] * w.y; }
    }
    float* dst = part + (size_t)ky * 160000;
#pragma unroll
    for (int m = 0; m < 16; ++m) {
        float2 o; o.x = acc0[m]; o.y = acc1[m];
        *reinterpret_cast<float2*>(dst + (size_t)m * FLATD + col) = o;
    }
}

// ---------- K2b: reduce 25 partials -> pre[16,10000] ----------
__global__ __launch_bounds__(256) void reduce_pre(const float* __restrict__ part, float* __restrict__ pre) {
    int e = blockIdx.x * 256 + threadIdx.x;   // 160000
    float s = 0.f;
#pragma unroll
    for (int p = 0; p < 25; ++p) s += part[(size_t)p * 160000 + e];
    pre[e] = s;
}

// ---------- K3: symmetrize + sigmoid + row stats (grid 16x2, 50 rows per block) ----------
__global__ __launch_bounds__(256) void sym_stats(const float* __restrict__ pre, const float* __restrict__ gbb,
                                                 float* __restrict__ adjsym, float* __restrict__ bft) {
    __shared__ float s_adj[50][NROI + 1];
    int b = blockIdx.x;
    int i0 = blockIdx.y * 50;
    const float* pb = pre + (size_t)b * FLATD;
    for (int idx = threadIdx.x; idx < 50 * NROI; idx += 256) {
        int i = i0 + idx / NROI, j = idx % NROI;
        float p = pb[i * NROI + j] + gbb[i * NROI + j];
        float q = pb[j * NROI + i] + gbb[j * NROI + i];
        float v = 0.5f * (sigmoidf(p) + sigmoidf(q));
        s_adj[i - i0][j] = v;
        adjsym[(size_t)b * FLATD + i * NROI + j] = v;
    }
    __syncthreads();
    if (threadIdx.x < 50) {
        int i = threadIdx.x;
        float sum = 0.f, sumsq = 0.f;
        for (int j = 0; j < NROI; ++j) { float v = s_adj[i][j]; sum += v; sumsq += v * v; }
        float mean = sum * 0.01f;
        float var = (sumsq - sum * sum * 0.01f) * (1.0f / 99.0f);
        var = fmaxf(var, 0.f);
        bft[(b * NROI + i0 + i) * 2 + 0] = mean;
        bft[(b * NROI + i0 + i) * 2 + 1] = sqrtf(var) + 1e-6f;
    }
}

// ---------- K4: exact 0.75-quantile via register radix-select ----------
// block 512, each thread holds 20 values; ranks 7499 & 7500 of 10000 (ascending)
__global__ __launch_bounds__(512) void quantile_radix(const float* __restrict__ adjsym, float* __restrict__ thr) {
    __shared__ int red[8];
    int b = blockIdx.x;
    int tid = threadIdx.x;
    unsigned v[20];
    const unsigned* src = (const unsigned*)(adjsym + (size_t)b * FLATD);
#pragma unroll
    for (int s = 0; s < 20; ++s) {
        int idx = s * 512 + tid;
        v[s] = (idx < FLATD) ? src[idx] : 0x7F800000u;   // +inf pad (all vals positive, <1)
    }
    float out[2];
    for (int rsel = 0; rsel < 2; ++rsel) {
        int rem = 7499 + rsel;
        unsigned prefix = 0;
        for (int bit = 30; bit >= 0; --bit) {
            unsigned pshift = prefix >> (bit + 1);
            int c = 0;
#pragma unroll
            for (int s = 0; s < 20; ++s) {
                unsigned x = v[s];
                c += (((x >> (bit + 1)) == pshift) && (((x >> bit) & 1u) == 0u)) ? 1 : 0;
            }
#pragma unroll
            for (int o = 32; o > 0; o >>= 1) c += __shfl_down(c, o, 64);
            if ((tid & 63) == 0) red[tid >> 6] = c;
            __syncthreads();
            int total = red[0] + red[1] + red[2] + red[3] + red[4] + red[5] + red[6] + red[7];
            __syncthreads();
            if (rem >= total) { rem -= total; prefix |= 1u << bit; }
        }
        union { unsigned u; float f; } cv; cv.u = prefix;
        out[rsel] = cv.f;
    }
    if (tid == 0) thr[b] = out[0] + 0.25f * (out[1] - out[0]);
}

// ---------- K5: feature enhancer + LayerNorm -> x0 [1600,16] ----------
__global__ __launch_bounds__(256) void enhancer(const float* __restrict__ bft,
                                                const float* __restrict__ W1, const float* __restrict__ b1,
                                                const float* __restrict__ W2, const float* __restrict__ b2,
                                                const float* __restrict__ g, const float* __restrict__ beta,
                                                float* __restrict__ x0) {
    int idx = blockIdx.x * 256 + threadIdx.x;
    if (idx >= BATCH * NROI) return;
    float f0 = bft[idx * 2 + 0], f1 = bft[idx * 2 + 1];
    float h8[8];
#pragma unroll
    for (int u = 0; u < 8; ++u) h8[u] = geluf(W1[u] * f0 + W1[8 + u] * f1 + b1[u]);
    float o[16];
    float mu = 0.f;
#pragma unroll
    for (int v = 0; v < 16; ++v) {
        float t = b2[v];
#pragma unroll
        for (int u = 0; u < 8; ++u) t += h8[u] * W2[u * 16 + v];
        o[v] = t; mu += t;
    }
    mu *= (1.0f / 16.0f);
    float var = 0.f;
#pragma unroll
    for (int v = 0; v < 16; ++v) { float d = o[v] - mu; var += d * d; }
    var *= (1.0f / 16.0f);
    float inv = rsqrtf(var + 1e-5f);
#pragma unroll
    for (int v = 0; v < 16; ++v) x0[idx * 16 + v] = (o[v] - mu) * inv * g[v] + beta[v];
}

// ---------- K6: fp32 tiled GEMM (layer 1, K=16), fused L/R via blockIdx.z ----------
__global__ __launch_bounds__(256) void proj_gemm(const float* __restrict__ X,
                                                 const float* __restrict__ WL, const float* __restrict__ WR,
                                                 const float* __restrict__ biasL, const float* __restrict__ biasR,
                                                 float* __restrict__ outL, float* __restrict__ outR,
                                                 int K, int Nout) {
    __shared__ float As[16][65];
    __shared__ float Bs[16][128];
    const float* W = blockIdx.z ? WR : WL;
    const float* bias = blockIdx.z ? biasR : biasL;
    float* out = blockIdx.z ? outR : outL;
    int tid = threadIdx.x;
    int tm = tid & 15, tn = tid >> 4;
    int m0 = blockIdx.x * 64, n0 = blockIdx.y * 128;
    float acc[4][8];
#pragma unroll
    for (int r = 0; r < 4; ++r)
#pragma unroll
        for (int c = 0; c < 8; ++c) acc[r][c] = 0.f;
    for (int k0 = 0; k0 < K; k0 += 16) {
        for (int e = tid; e < 64 * 16; e += 256) {
            int kk = e & 15, mm = e >> 4;
            As[kk][mm] = X[(size_t)(m0 + mm) * K + k0 + kk];
        }
        for (int e = tid; e < 16 * 128; e += 256) {
            int nn = e & 127, kk = e >> 7;
            Bs[kk][nn] = W[(size_t)(k0 + kk) * Nout + n0 + nn];
        }
        __syncthreads();
#pragma unroll
        for (int kk = 0; kk < 16; ++kk) {
            float a[4], bb[8];
#pragma unroll
            for (int r = 0; r < 4; ++r) a[r] = As[kk][tm * 4 + r];
#pragma unroll
            for (int c = 0; c < 8; ++c) bb[c] = Bs[kk][tn * 8 + c];
#pragma unroll
            for (int r = 0; r < 4; ++r)
#pragma unroll
                for (int c = 0; c < 8; ++c) acc[r][c] += a[r] * bb[c];
        }
        __syncthreads();
    }
#pragma unroll
    for (int r = 0; r < 4; ++r)
#pragma unroll
        for (int c = 0; c < 8; ++c)
            out[(size_t)(m0 + tm * 4 + r) * Nout + n0 + tn * 8 + c] = acc[r][c] + bias[n0 + tn * 8 + c];
}

// ---------- K6b: convert fp32 -> bf16 ----------
__global__ __launch_bounds__(256) void convX(const float* __restrict__ in, short* __restrict__ out) {
    int e = (blockIdx.x * 256 + threadIdx.x) * 4;
    float4 v = *reinterpret_cast<const float4*>(in + e);
    s16x4 o;
    o[0] = f2bf(v.x); o[1] = f2bf(v.y); o[2] = f2bf(v.z); o[3] = f2bf(v.w);
    *reinterpret_cast<s16x4*>(out + e) = o;
}

// ---------- K6c: transpose + convert W [K,N] fp32 -> Wt [N,K] bf16 ----------
__global__ __launch_bounds__(256) void convT(const float* __restrict__ in, short* __restrict__ out,
                                             int K, int N) {
    __shared__ float t[32][33];
    int n0 = blockIdx.x * 32, k0 = blockIdx.y * 32;
    int tx = threadIdx.x & 31, ty = threadIdx.x >> 5;
#pragma unroll
    for (int i = 0; i < 32; i += 8)
        t[ty + i][tx] = in[(size_t)(k0 + ty + i) * N + n0 + tx];
    __syncthreads();
#pragma unroll
    for (int i = 0; i < 32; i += 8)
        out[(size_t)(n0 + ty + i) * K + k0 + tx] = f2bf(t[tx][ty + i]);
}

// ---------- K6d: bf16 MFMA GEMM out[M,N] = Xb[M,K] @ Wt[N,K]^T + bias ----------
__global__ __launch_bounds__(256) void mfma_proj(const short* __restrict__ Xb,
                                                 const short* __restrict__ WtL, const short* __restrict__ WtR,
                                                 const float* __restrict__ biasL, const float* __restrict__ biasR,
                                                 float* __restrict__ outL, float* __restrict__ outR,
                                                 int K, int N) {
    __shared__ short As[64 * 40];
    __shared__ short Bs[64 * 40];
    const short* Wt  = blockIdx.z ? WtR : WtL;
    const float* bias = blockIdx.z ? biasR : biasL;
    float* out = blockIdx.z ? outR : outL;
    int m0 = blockIdx.x * 64, n0 = blockIdx.y * 64;
    int tid = threadIdx.x;
    int row = tid >> 2, part = tid & 3;
    int lane = tid & 63, wave = tid >> 6;
    int wm = wave & 1, wn = wave >> 1;
    int quad = lane >> 4, l16 = lane & 15;
    f32x4 acc00 = {}, acc01 = {}, acc10 = {}, acc11 = {};
    const short* gA = Xb + (size_t)(m0 + row) * K + part * 8;
    const short* gB = Wt + (size_t)(n0 + row) * K + part * 8;
    short* sA = As + row * 40 + part * 8;
    short* sB = Bs + row * 40 + part * 8;
    const short* fA = As + (wm * 32 + l16) * 40 + quad * 8;
    const short* fB = Bs + (wn * 32 + l16) * 40 + quad * 8;
    for (int k0 = 0; k0 < K; k0 += 32) {
        *reinterpret_cast<s16x8*>(sA) = *reinterpret_cast<const s16x8*>(gA + k0);
        *reinterpret_cast<s16x8*>(sB) = *reinterpret_cast<const s16x8*>(gB + k0);
        __syncthreads();
        s16x8 a0 = *reinterpret_cast<const s16x8*>(fA);
        s16x8 a1 = *reinterpret_cast<const s16x8*>(fA + 16 * 40);
        s16x8 b0 = *reinterpret_cast<const s16x8*>(fB);
        s16x8 b1 = *reinterpret_cast<const s16x8*>(fB + 16 * 40);
        acc00 = __builtin_amdgcn_mfma_f32_16x16x32_bf16(a0, b0, acc00, 0, 0, 0);
        acc01 = __builtin_amdgcn_mfma_f32_16x16x32_bf16(a0, b1, acc01, 0, 0, 0);
        acc10 = __builtin_amdgcn_mfma_f32_16x16x32_bf16(a1, b0, acc10, 0, 0, 0);
        acc11 = __builtin_amdgcn_mfma_f32_16x16x32_bf16(a1, b1, acc11, 0, 0, 0);
        __syncthreads();
    }
#pragma unroll
    for (int tm = 0; tm < 2; ++tm)
#pragma unroll
        for (int tn = 0; tn < 2; ++tn) {
            const f32x4& a = tm == 0 ? (tn == 0 ? acc00 : acc01) : (tn == 0 ? acc10 : acc11);
            int mbase = m0 + wm * 32 + tm * 16 + quad * 4;
            int n = n0 + wn * 32 + tn * 16 + l16;
            float bv = bias[n];
#pragma unroll
            for (int r = 0; r < 4; ++r)
                out[(size_t)(mbase + r) * N + n] = a[r] + bv;
        }
}

// ---------- K7: GATv2 scores + masked softmax -> alpha_T[b,h,j,i] ----------
// grid (B*H, 100/itile), block 128 (lane = j)
__global__ __launch_bounds__(128) void score_softmax(const float* __restrict__ xl, const float* __restrict__ xr,
                                                     const float* __restrict__ att, const float* __restrict__ adjsym,
                                                     const float* __restrict__ thr, float* __restrict__ alpha,
                                                     int H, int C, int self_loop, int itile) {
    __shared__ float e_lds[25][101];
    int bh = blockIdx.x;
    int b = bh / H, h = bh % H;
    int i0 = blockIdx.y * itile;
    int j = threadIdx.x;
    const float* xlrow = xl + ((size_t)(b * NROI + (j < NROI ? j : 0)) * H + h) * C;

    for (int cc = 0; cc < C; cc += 32) {
        float xlr[32];
        if (j < NROI) {
#pragma unroll
            for (int t = 0; t < 32; ++t) xlr[t] = xlrow[cc + t];
        }
        const float* attp = att + h * C + cc;           // uniform -> SGPR
        for (int i = 0; i < itile; ++i) {
            const float* xrrow = xr + ((size_t)(b * NROI + i0 + i) * H + h) * C + cc;  // uniform -> SGPR
            float s = 0.f;
#pragma unroll
            for (int t = 0; t < 32; ++t) {
                float z = xlr[t] + xrrow[t];
                z = fmaxf(z, 0.2f * z);
                s += attp[t] * z;
            }
            if (j < NROI) {
                if (cc == 0) e_lds[i][j] = s; else e_lds[i][j] += s;
            }
        }
    }
    __syncthreads();
    if (threadIdx.x < itile) {
        int i = threadIdx.x;
        int gi = i0 + i;
        const float* arow = adjsym + (size_t)b * FLATD + gi * NROI;
        float tb = thr[b];
        float mx = -3.0e38f;
        for (int jj = 0; jj < NROI; ++jj) {
            float e = e_lds[i][jj];
            bool edge = (arow[jj] > tb) || (self_loop && jj == gi);
            float em = edge ? e : -1.0e9f;
            e_lds[i][jj] = em;
            mx = fmaxf(mx, em);
        }
        float sum = 0.f;
        for (int jj = 0; jj < NROI; ++jj) sum += expf(e_lds[i][jj] - mx);
        float inv = 1.0f / sum;
        float* ab = alpha + (size_t)(b * H + h) * FLATD + gi;
        for (int jj = 0; jj < NROI; ++jj) {
            float em = e_lds[i][jj];
            ab[jj * NROI] = (em > -0.5e9f) ? expf(em - mx) * inv : 0.0f;
        }
    }
}

// ---------- K8: aggregation ----------
__global__ __launch_bounds__(128) void agg_kernel(const float* __restrict__ xl, const float* __restrict__ alpha,
                                                  const float* __restrict__ bias, float* __restrict__ yout,
                                                  float* __restrict__ pool_out, int H, int C, int pool) {
    __shared__ float s_xl[NROI * 128];
    int bh = blockIdx.x;
    int b = bh / H, h = bh % H;
    int ch = blockIdx.y;
    int i0 = blockIdx.z * 25;
    int tid = threadIdx.x;
    for (int e = tid; e < NROI * 128; e += 128) {
        int jj = e >> 7, t = e & 127;
        s_xl[e] = xl[((size_t)(b * NROI + jj) * H + h) * C + ch * 128 + t];
    }
    __syncthreads();
    int cglob = ch * 128 + tid;
    float bval = bias[h * C + cglob];
    const float* ap = alpha + (size_t)(b * H + h) * FLATD;
    float pacc = 0.f;
    for (int ib = 0; ib < 25; ib += 8) {
        int nb = (25 - ib) >= 8 ? 8 : (25 - ib);
        float acc[8] = {0.f, 0.f, 0.f, 0.f, 0.f, 0.f, 0.f, 0.f};
        if (nb == 8) {
            for (int jj = 0; jj < NROI; ++jj) {
                float xlv = s_xl[jj * 128 + tid];
                const float* ar = ap + jj * NROI + i0 + ib;
#pragma unroll
                for (int t = 0; t < 8; ++t) acc[t] += ar[t] * xlv;
            }
        } else {
            for (int jj = 0; jj < NROI; ++jj)
                acc[0] += ap[jj * NROI + i0 + ib] * s_xl[jj * 128 + tid];
        }
        for (int t = 0; t < nb; ++t) {
            int gi = i0 + ib + t;
            float v = geluf(acc[t] + bval);
            if (pool) pacc += 0.01f * v;
            else yout[((size_t)(b * NROI + gi) * H + h) * C + cglob] = v;
        }
    }
    if (pool) atomicAdd(pool_out + b * 128 + cglob, pacc);
}

// ---------- launcher ----------
extern "C" void kernel_launch(void* const* d_in, const int* in_sizes, int n_in,
                              void* d_out, int out_size, void* d_ws, size_t ws_size,
                              hipStream_t stream) {
    const float* A    = (const float*)d_in[0];
    const float* gbW  = (const float*)d_in[1];
    const float* gbb  = (const float*)d_in[2];
    const float* feW1 = (const float*)d_in[3];
    const float* feb1 = (const float*)d_in[4];
    const float* feW2 = (const float*)d_in[5];
    const float* feb2 = (const float*)d_in[6];
    const float* feg  = (const float*)d_in[7];
    const float* febt = (const float*)d_in[8];
    const float* Wl1  = (const float*)d_in[9];
    const float* bl1  = (const float*)d_in[10];
    const float* Wr1  = (const float*)d_in[11];
    const float* br1  = (const float*)d_in[12];
    const float* att1 = (const float*)d_in[13];
    const float* bias1= (const float*)d_in[14];
    const float* Wl2  = (const float*)d_in[15];
    const float* bl2  = (const float*)d_in[16];
    const float* Wr2  = (const float*)d_in[17];
    const float* br2  = (const float*)d_in[18];
    const float* att2 = (const float*)d_in[19];
    const float* bias2= (const float*)d_in[20];
    const float* Wl3  = (const float*)d_in[21];
    const float* bl3  = (const float*)d_in[22];
    const float* Wr3  = (const float*)d_in[23];
    const float* br3  = (const float*)d_in[24];
    const float* att3 = (const float*)d_in[25];
    const float* bias3= (const float*)d_in[26];

    float* ws = (float*)d_ws;
    float* At    = ws + 0;          // 160000
    float* pre   = ws + 160000;     // 160000
    float* adj   = ws + 320000;     // 160000
    float* thr   = ws + 480000;     // 16
    float* bft   = ws + 480016;     // 3200
    float* x0    = ws + 483216;     // 25600
    float* xlbuf = ws + 508816;     // 1638400
    float* xrbuf = ws + 2147216;    // 1638400
    float* ybuf  = ws + 3785616;    // 1638400
    float* alpha = ws + 5424016;    // 1280000  (Xb aliases here)
    short* Xb    = (short*)(ws + 5424016);
    short* Wt2l  = (short*)(ws + 6704016);
    short* Wt2r  = (short*)(ws + 7228304);
    short* Wt3l  = (short*)(ws + 7752592);
    short* Wt3r  = (short*)(ws + 7818128);
    float* prep  = ws + 7883664;    // 25*160000 = 4,000,000  (end ~47.5 MB)

    hipMemsetAsync(d_out, 0, (size_t)out_size * sizeof(float), stream);

    transpose_A<<<625, 256, 0, stream>>>(A, At);
    gemm1_part<<<dim3(20, 25), 256, 0, stream>>>(At, gbW, prep);
    reduce_pre<<<625, 256, 0, stream>>>(prep, pre);
    sym_stats<<<dim3(BATCH, 2), 256, 0, stream>>>(pre, gbb, adj, bft);
    quantile_radix<<<BATCH, 512, 0, stream>>>(adj, thr);
    enhancer<<<7, 256, 0, stream>>>(bft, feW1, feb1, feW2, feb2, feg, febt, x0);

    // weight conversions (constant inputs, redone per call)
    convT<<<dim3(32, 32), 256, 0, stream>>>(Wl2, Wt2l, 1024, 1024);
    convT<<<dim3(32, 32), 256, 0, stream>>>(Wr2, Wt2r, 1024, 1024);
    convT<<<dim3(4, 32), 256, 0, stream>>>(Wl3, Wt3l, 1024, 128);
    convT<<<dim3(4, 32), 256, 0, stream>>>(Wr3, Wt3r, 1024, 128);

    // layer 1: H=8, C=128, no self loops (K=16 -> fp32 path)
    proj_gemm<<<dim3(25, 8, 2), 256, 0, stream>>>(x0, Wl1, Wr1, bl1, br1, xlbuf, xrbuf, 16, 1024);
    score_softmax<<<dim3(128, 4), 128, 0, stream>>>(xlbuf, xrbuf, att1, adj, thr, alpha, 8, 128, 0, 25);
    agg_kernel<<<dim3(128, 1, 4), 128, 0, stream>>>(xlbuf, alpha, bias1, ybuf, nullptr, 8, 128, 0);

    // layer 2: H=4, C=256, self loops (MFMA path)
    convX<<<1600, 256, 0, stream>>>(ybuf, Xb);
    mfma_proj<<<dim3(25, 16, 2), 256, 0, stream>>>(Xb, Wt2l, Wt2r, bl2, br2, xlbuf, xrbuf, 1024, 1024);
    score_softmax<<<dim3(64, 4), 128, 0, stream>>>(xlbuf, xrbuf, att2, adj, thr, alpha, 4, 256, 1, 25);
    agg_kernel<<<dim3(64, 2, 4), 128, 0, stream>>>(xlbuf, alpha, bias2, ybuf, nullptr, 4, 256, 0);

    // layer 3: H=1, C=128, self loops (MFMA path), mean-pool into d_out
    convX<<<1600, 256, 0, stream>>>(ybuf, Xb);
    mfma_proj<<<dim3(25, 2, 2), 256, 0, stream>>>(Xb, Wt3l, Wt3r, bl3, br3, xlbuf, xrbuf, 1024, 128);
    score_softmax<<<dim3(16, 10), 128, 0, stream>>>(xlbuf, xrbuf, att3, adj, thr, alpha, 1, 128, 1, 10);
    agg_kernel<<<dim3(16, 1, 4), 128, 0, stream>>>(xlbuf, alpha, bias3, nullptr, (float*)d_out, 1, 128, 1);
}